// Round 12
// baseline (39.643 us; speedup 1.0000x reference)
//
#include <hip/hip_runtime.h>
#include <cstdint>

// Problem constants (match reference)
#define BB 32
#define NN 32768
#define CC 21
#define K1_BLK 256
#define PPT 2                                  // tiles (priors) per thread
#define TILE (K1_BLK * PPT)                    // 512 priors per block
#define K1_GRID ((BB * NN) / TILE)             // 2048
#define BLKROW (NN / TILE)                     // 64 k1-blocks per row
#define WST 1536                               // floats per wave-tile stage (6 KB)

// K2 geometry
#define K2T 1024
#define NC 16                                  // level-1 hist copies

// native transcendentals (1-ulp; output threshold 0.39 absolute -> huge slack)
__device__ __forceinline__ float fexp2(float x) {
    float r; asm("v_exp_f32 %0, %1" : "=v"(r) : "v"(x)); return r;
}
__device__ __forceinline__ float flog2(float x) {
    float r; asm("v_log_f32 %0, %1" : "=v"(r) : "v"(x)); return r;
}

// ---------------------------------------------------------------------------
// K1 v9: coalesced global->LDS staging (TA-friendly 16B/lane contiguous)
// + 2-deep counted-vmcnt pipeline per wave (T3/T4 pattern): stage BOTH
// tiles (12 loads in flight), vmcnt(6) -> compute tile0 while tile1
// streams, vmcnt(0) -> compute tile1. Divergent pred/gt loads issued only
// after the last counted wait so the count stays exact. Wave-private LDS,
// no block barrier on the memory path. Math bit-identical to v5.
// ---------------------------------------------------------------------------
__global__ __launch_bounds__(K1_BLK) void k1_compute(
    const float* __restrict__ conf, const float* __restrict__ pred,
    const int* __restrict__ labels, const float* __restrict__ gt,
    unsigned* __restrict__ keys, float* __restrict__ pce,
    float* __restrict__ psl1, int* __restrict__ pcnt,
    double* __restrict__ gsum, unsigned* __restrict__ done)
{
    __shared__ __align__(16) float lconf[8 * WST];   // 48 KB: [wave][tile][1536]
    __shared__ float wce[4], wsl[4];
    __shared__ int   wcnt[4];

    const int tid = threadIdx.x;
    const int lane = tid & 63;
    const int w = tid >> 6;
    const int base = blockIdx.x * TILE;              // first prior of block
    const size_t p0 = (size_t)base + w * 64 + lane;  // tile0 prior
    const size_t p1 = p0 + K1_BLK;                   // tile1 prior

    if (blockIdx.x == 0 && tid == 0) { *done = 0u; *gsum = 0.0; }

    // labels first (compiler's counted wait for these won't drain staging)
    const int lab0 = labels[p0];
    const int lab1 = labels[p1];

    // ---- stage BOTH tiles: 64 priors x 84 B = 5376 B = 336 x 16B slots
    // -> 6 instrs/tile (last clamped; dup lands in the 768 B pad).
    float* l0 = lconf + (w * 2 + 0) * WST;
    float* l1 = lconf + (w * 2 + 1) * WST;
    const char* g0 = (const char*)(conf + (size_t)(base + w * 64) * CC);
    const char* g1 = (const char*)(conf + (size_t)(base + K1_BLK + w * 64) * CC);
#pragma unroll
    for (int s = 0; s < 6; ++s) {
        int slot = s * 64 + lane;
        if (s == 5) slot = (slot > 335) ? 335 : slot;
        __builtin_amdgcn_global_load_lds(
            (const __attribute__((address_space(1))) unsigned*)(g0 + (size_t)slot * 16),
            (__attribute__((address_space(3))) unsigned*)(l0 + s * 256), 16, 0, 0);
    }
#pragma unroll
    for (int s = 0; s < 6; ++s) {
        int slot = s * 64 + lane;
        if (s == 5) slot = (slot > 335) ? 335 : slot;
        __builtin_amdgcn_global_load_lds(
            (const __attribute__((address_space(1))) unsigned*)(g1 + (size_t)slot * 16),
            (__attribute__((address_space(3))) unsigned*)(l1 + s * 256), 16, 0, 0);
    }

    const bool pos0 = lab0 > 0;
    const bool pos1 = lab1 > 0;

    // ---- wait tile0 only (tile1's 6 loads stay in flight)
    asm volatile("s_waitcnt vmcnt(6)" ::: "memory");
    __builtin_amdgcn_sched_barrier(0);

    const float* my0 = l0 + lane * CC;    // stride 21: 2 lanes/bank, free
    float s0 = 0.f;
#pragma unroll
    for (int c = 0; c < CC; ++c) s0 += fexp2(my0[c] * 1.44269504f);
    const float lse0 = 0.6931471805599453f * flog2(s0);
    const float c00 = my0[0];
    const float cl0 = my0[lab0];          // dynamic ds_read, lab in [0,21)
    const float mining0 = fmaxf(lse0 - c00, 0.f);
    keys[p0] = pos0 ? 0u : __float_as_uint(mining0);
    float ce = pos0 ? (lse0 - cl0) : 0.f;
    int cnt = pos0 ? 1 : 0;

    // ---- wait tile1
    asm volatile("s_waitcnt vmcnt(0)" ::: "memory");
    __builtin_amdgcn_sched_barrier(0);

    const float* my1 = l1 + lane * CC;
    float s1 = 0.f;
#pragma unroll
    for (int c = 0; c < CC; ++c) s1 += fexp2(my1[c] * 1.44269504f);
    const float lse1 = 0.6931471805599453f * flog2(s1);
    const float c10 = my1[0];
    const float cl1 = my1[lab1];
    const float mining1 = fmaxf(lse1 - c10, 0.f);
    keys[p1] = pos1 ? 0u : __float_as_uint(mining1);
    ce += pos1 ? (lse1 - cl1) : 0.f;
    cnt += pos1 ? 1 : 0;

    // ---- sparse (~3%) SmoothL1 AFTER counted waits (divergent loads would
    // otherwise corrupt the vmcnt arithmetic above)
    float sl = 0.f;
    if (pos0) {
        const float* pp = pred + p0 * 5;
        const float* gg = gt + p0 * 5;
#pragma unroll
        for (int j = 0; j < 5; ++j) {
            float d = fabsf(pp[j] - gg[j]);
            sl += (d < 1.f) ? 0.5f * d * d : (d - 0.5f);
        }
    }
    if (pos1) {
        const float* pp = pred + p1 * 5;
        const float* gg = gt + p1 * 5;
#pragma unroll
        for (int j = 0; j < 5; ++j) {
            float d = fabsf(pp[j] - gg[j]);
            sl += (d < 1.f) ? 0.5f * d * d : (d - 0.5f);
        }
    }

    // ---- deterministic block reduction (fixed trees)
#pragma unroll
    for (int d = 32; d > 0; d >>= 1) {
        ce  += __shfl_down(ce, d);
        sl  += __shfl_down(sl, d);
        cnt += __shfl_down(cnt, d);
    }
    if (lane == 0) { wce[w] = ce; wsl[w] = sl; wcnt[w] = cnt; }
    __syncthreads();
    if (tid == 0) {
        float tce = 0.f, tsl = 0.f; int tc = 0;
#pragma unroll
        for (int v = 0; v < 4; ++v) { tce += wce[v]; tsl += wsl[v]; tc += wcnt[v]; }
        pce[blockIdx.x]  = tce;
        psl1[blockIdx.x] = tsl;
        pcnt[blockIdx.x] = tc;     // non-atomic per-block count
    }
}

// ---------------------------------------------------------------------------
// Suffix-scan over 2048 bins (2 bins/thread) + crossing pick.
// ---------------------------------------------------------------------------
template <class GET>
__device__ __forceinline__ void sscan2048(
    GET get, unsigned* ss, unsigned* swsum,
    int* s_bin, int* s_above, unsigned want, int tid, int lane, int wid)
{
    const int b0 = 2047 - 2 * tid;     // descending scan order
    const int b1 = 2046 - 2 * tid;
    const unsigned m0 = get(b0), m1 = get(b1);
    unsigned v = m0 + m1;
#pragma unroll
    for (int d = 1; d < 64; d <<= 1) {
        unsigned u = __shfl_up(v, d);
        if (lane >= d) v += u;
    }
    if (lane == 63) swsum[wid] = v;
    __syncthreads();
    if (wid == 0) {
        unsigned wv = (lane < 16) ? swsum[lane] : 0;
#pragma unroll
        for (int d = 1; d < 16; d <<= 1) {
            unsigned u = __shfl_up(wv, d);
            if (lane >= d) wv += u;
        }
        if (lane < 16) swsum[lane] = wv;
    }
    __syncthreads();
    const unsigned off = wid ? swsum[wid - 1] : 0;
    const unsigned incl = off + v;     // suffix through b1
    const unsigned sb0 = incl - m1;    // suffix through b0
    ss[b0] = sb0;
    ss[b1] = incl;
    __syncthreads();
    if (sb0 >= want && (b0 == 2047 || ss[b0 + 1] < want)) {
        *s_bin = b0; *s_above = (b0 == 2047) ? 0 : (int)ss[b0 + 1];
    }
    if (incl >= want && ss[b1 + 1] < want) {
        *s_bin = b1; *s_above = (int)ss[b1 + 1];
    }
    __syncthreads();
}

// ---------------------------------------------------------------------------
// K2 v8 (R11-best, byte-identical): register-resident 2-level select with
// in-bin-mean tail (error ~1e-5 << 0.39) + fence-free k3 fold.
// ---------------------------------------------------------------------------
__global__ __launch_bounds__(K2T, 8) void k2_select(
    const unsigned* __restrict__ keys, const int* __restrict__ pcnt,
    const float* __restrict__ pce, const float* __restrict__ psl1,
    double* __restrict__ gsum, unsigned* __restrict__ done,
    float* __restrict__ out)
{
    const int b = blockIdx.x;
    const int tid = threadIdx.x;
    const int lane = tid & 63;
    const int wid = tid >> 6;
    const unsigned* rk = keys + (size_t)b * NN;

    __shared__ unsigned h1[1024 * NC];  // 64 KB (reused for level 2)
    __shared__ unsigned ss[2048];       // 8 KB suffix sums
    __shared__ unsigned swsum[16];
    __shared__ double sdA[16], sdB[16];
    __shared__ int sdI[16];
    __shared__ int s_bin, s_above, s_last;
    __shared__ unsigned s_want;

    // ---- one coalesced read: 8 x uint4 per thread -> 32 keys in VGPRs
    uint4 kv[8];
    const uint4* rk4 = reinterpret_cast<const uint4*>(rk);
#pragma unroll
    for (int j = 0; j < 8; ++j) kv[j] = rk4[tid + j * K2T];

    // want = min(3 * row positives, NN)
    if (wid == 0) {
        int c = pcnt[b * BLKROW + lane];          // BLKROW == 64 == wave
#pragma unroll
        for (int d = 32; d > 0; d >>= 1) c += __shfl_down(c, d);
        if (lane == 0) s_want = (unsigned)((3 * c > NN) ? NN : 3 * c);
    }
    for (int i = tid; i < 1024 * NC; i += K2T) h1[i] = 0;
    __syncthreads();
    const unsigned want = s_want;

    double rowval = 0.0;    // this row's selected-negative CE sum (tid 0 only)
    if (want > 0) {
        // ---- level 1: 1024-bin hist of bits[31:21]
        const unsigned cp = lane & (NC - 1);
#pragma unroll
        for (int j = 0; j < 8; ++j) {
            atomicAdd(&h1[((kv[j].x >> 21) << 4) | cp], 1u);
            atomicAdd(&h1[((kv[j].y >> 21) << 4) | cp], 1u);
            atomicAdd(&h1[((kv[j].z >> 21) << 4) | cp], 1u);
            atomicAdd(&h1[((kv[j].w >> 21) << 4) | cp], 1u);
        }
        __syncthreads();

        // ---- level-1 scan: one bin/thread, descending suffix sums
        {
            const int bn = 1023 - tid;
            unsigned mv = 0;
#pragma unroll
            for (int c = 0; c < NC; ++c) mv += h1[(bn << 4) | c];
            unsigned v = mv;
#pragma unroll
            for (int d = 1; d < 64; d <<= 1) {
                unsigned u = __shfl_up(v, d);
                if (lane >= d) v += u;
            }
            if (lane == 63) swsum[wid] = v;
            __syncthreads();
            if (wid == 0) {
                unsigned wv = (lane < 16) ? swsum[lane] : 0;
#pragma unroll
                for (int d = 1; d < 16; d <<= 1) {
                    unsigned u = __shfl_up(wv, d);
                    if (lane >= d) wv += u;
                }
                if (lane < 16) swsum[lane] = wv;
            }
            __syncthreads();
            const unsigned incl = (wid ? swsum[wid - 1] : 0) + v;
            ss[bn] = incl;
            __syncthreads();
            if (incl >= want && (bn == 1023 || ss[bn + 1] < want)) {
                s_bin = bn; s_above = (bn == 1023) ? 0 : (int)ss[bn + 1];
            }
            __syncthreads();
        }
        const unsigned bsel1 = (unsigned)s_bin;
        const unsigned want1 = want - (unsigned)s_above;

        // ---- level 2: bits[20:10] of in-bin keys, straight from registers
        for (int i = tid; i < 4096; i += K2T) h1[i] = 0;
        __syncthreads();
        const unsigned c2 = lane & 1;
#pragma unroll
        for (int j = 0; j < 8; ++j) {
#define L2ADD(K) if (((K) >> 21) == bsel1) \
            atomicAdd(&h1[((((K) >> 10) & 0x7FFu) << 1) | c2], 1u);
            L2ADD(kv[j].x) L2ADD(kv[j].y) L2ADD(kv[j].z) L2ADD(kv[j].w)
#undef L2ADD
        }
        __syncthreads();
        sscan2048([&](int bn) { return h1[bn << 1] + h1[(bn << 1) | 1]; },
                  ss, swsum, &s_bin, &s_above, want1, tid, lane, wid);
        const unsigned bsel2 = (unsigned)s_bin;
        const unsigned want2 = want1 - (unsigned)s_above;   // 1 <= want2 <= cnt2
        const unsigned pref = (bsel1 << 11) | bsel2;        // key bits[31:10]

        // ---- final register pass: exact sum above bin + in-bin sum/count
        double aboveS = 0.0, inS = 0.0;
        int inC = 0;
#pragma unroll
        for (int j = 0; j < 8; ++j) {
#define FIN(K) { const unsigned hp = (K) >> 10; \
            if (hp > pref) aboveS += (double)__uint_as_float(K); \
            else if (hp == pref) { inS += (double)__uint_as_float(K); inC++; } }
            FIN(kv[j].x) FIN(kv[j].y) FIN(kv[j].z) FIN(kv[j].w)
#undef FIN
        }
#pragma unroll
        for (int d = 32; d > 0; d >>= 1) {
            aboveS += __shfl_down(aboveS, d);
            inS    += __shfl_down(inS, d);
            inC    += __shfl_down(inC, d);
        }
        if (lane == 0) { sdA[wid] = aboveS; sdB[wid] = inS; sdI[wid] = inC; }
        __syncthreads();
        if (tid == 0) {
            double tA = 0.0, tB = 0.0; int tC = 0;
#pragma unroll
            for (int w = 0; w < 16; ++w) { tA += sdA[w]; tB += sdB[w]; tC += sdI[w]; }
            rowval = tA + tB * ((double)want2 / (double)tC);
        }
    }

    // ---- fence-free completion (device-scope atomics; data-dependent order)
    if (tid == 0) {
        const double oldv = atomicAdd(gsum, rowval);
        unsigned inc = (__double_as_longlong(oldv) == 0x7FF7DEADBEEF0123LL)
                           ? 2u : 1u;   // always 1; unprovable -> dep kept
        const unsigned old = atomicAdd(done, inc);
        s_last = (old == BB - 1) ? 1 : 0;
    }
    __syncthreads();

    // ---- last block: global reduction of k1 partials + output write
    if (s_last) {
        double ce = 0.0, sl = 0.0; int np = 0;
        for (int i = tid; i < K1_GRID; i += K2T) {   // 2 iterations
            ce += (double)pce[i];
            sl += (double)psl1[i];
            np += pcnt[i];
        }
#pragma unroll
        for (int d = 32; d > 0; d >>= 1) {
            ce += __shfl_down(ce, d);
            sl += __shfl_down(sl, d);
            np += __shfl_down(np, d);
        }
        if (lane == 0) { sdA[wid] = ce; sdB[wid] = sl; sdI[wid] = np; }
        __syncthreads();
        if (tid == 0) {
            double tce = 0.0, tsl = 0.0; int tnp = 0;
#pragma unroll
            for (int w = 0; w < 16; ++w) { tce += sdA[w]; tsl += sdB[w]; tnp += sdI[w]; }
            const double ns = atomicAdd(gsum, 0.0);   // full sum (all 32 done)
            const double npos = (double)tnp;
            out[0] = (float)(tsl / npos);             // smooth_l1_loss / n_pos
            out[1] = (float)((tce + ns) / npos);      // classification_loss / n_pos
        }
    }
}

// ---------------------------------------------------------------------------
extern "C" void kernel_launch(void* const* d_in, const int* in_sizes, int n_in,
                              void* d_out, int out_size, void* d_ws, size_t ws_size,
                              hipStream_t stream)
{
    const float* conf   = (const float*)d_in[0];
    const float* pred   = (const float*)d_in[1];
    const int*   labels = (const int*)d_in[2];
    const float* gt     = (const float*)d_in[3];
    float* out = (float*)d_out;

    char* ws = (char*)d_ws;
    unsigned* keys = (unsigned*)ws;                  // 4 MB
    float*    pce  = (float*)(ws + 4194304);         // 8 KB
    float*    psl1 = (float*)(ws + 4202496);         // 8 KB
    int*      pcnt = (int*)(ws + 4210688);           // 8 KB
    double*   gsum = (double*)(ws + 4218880);        // 8 B
    unsigned* done = (unsigned*)(ws + 4218888);      // 4 B

    k1_compute<<<K1_GRID, K1_BLK, 0, stream>>>(conf, pred, labels, gt,
                                               keys, pce, psl1, pcnt,
                                               gsum, done);
    k2_select<<<BB, K2T, 0, stream>>>(keys, pcnt, pce, psl1,
                                      gsum, done, out);
}

// Round 13
// 37.434 us; speedup vs baseline: 1.0590x; 1.0590x over previous
//
#include <hip/hip_runtime.h>
#include <cstdint>

// Problem constants (match reference)
#define BB 32
#define NN 32768
#define CC 21
#define K1_BLK 256
#define PPT 2                                  // priors per thread
#define TILE (K1_BLK * PPT)                    // 512
#define K1_GRID ((BB * NN) / TILE)             // 2048
#define BLKROW (NN / TILE)                     // 64 k1-blocks per row

// K2 geometry
#define K2T 1024

typedef float f4 __attribute__((ext_vector_type(4)));

// native transcendentals (1-ulp; output threshold 0.39 absolute -> huge slack)
__device__ __forceinline__ float fexp2(float x) {
    float r; asm("v_exp_f32 %0, %1" : "=v"(r) : "v"(x)); return r;
}
__device__ __forceinline__ float flog2(float x) {
    float r; asm("v_log_f32 %0, %1" : "=v"(r) : "v"(x)); return r;
}

// ---------------------------------------------------------------------------
// K1 v5 (R11-best, byte-identical): register streaming, 2 priors/thread,
// all loads batched up-front. Block 0 zeroes k2's gsum/done.
// ---------------------------------------------------------------------------
__global__ __launch_bounds__(K1_BLK) void k1_compute(
    const float* __restrict__ conf, const float* __restrict__ pred,
    const int* __restrict__ labels, const float* __restrict__ gt,
    unsigned* __restrict__ keys, float* __restrict__ pce,
    float* __restrict__ psl1, int* __restrict__ pcnt,
    double* __restrict__ gsum, unsigned* __restrict__ done)
{
    __shared__ float wce[4], wsl[4];
    __shared__ int   wcnt[4];

    const int tid = threadIdx.x;
    const int lane = tid & 63;
    const int wid = tid >> 6;
    const size_t p0 = (size_t)blockIdx.x * TILE + tid;
    const size_t p1 = p0 + K1_BLK;

    if (blockIdx.x == 0 && tid == 0) { *done = 0u; *gsum = 0.0; }

    // ---- issue ALL loads up front, nothing consumed yet
    const int lab0 = labels[p0];
    const int lab1 = labels[p1];
    const float* cp0 = conf + p0 * CC;
    const float* cp1 = conf + p1 * CC;
    f4 A0, A1, A2, A3, A4, B0, B1, B2, B3, B4;
    __builtin_memcpy(&A0, cp0 +  0, 16);
    __builtin_memcpy(&A1, cp0 +  4, 16);
    __builtin_memcpy(&A2, cp0 +  8, 16);
    __builtin_memcpy(&A3, cp0 + 12, 16);
    __builtin_memcpy(&A4, cp0 + 16, 16);
    __builtin_memcpy(&B0, cp1 +  0, 16);
    __builtin_memcpy(&B1, cp1 +  4, 16);
    __builtin_memcpy(&B2, cp1 +  8, 16);
    __builtin_memcpy(&B3, cp1 + 12, 16);
    __builtin_memcpy(&B4, cp1 + 16, 16);
    const float a20 = cp0[20];
    const float b20 = cp1[20];

    const bool pos0 = lab0 > 0;
    const bool pos1 = lab1 > 0;

    // sparse (~3%) SmoothL1 for both priors
    float sl = 0.f;
    if (pos0) {
        const float* pp = pred + p0 * 5;
        const float* gg = gt + p0 * 5;
#pragma unroll
        for (int j = 0; j < 5; ++j) {
            float d = fabsf(pp[j] - gg[j]);
            sl += (d < 1.f) ? 0.5f * d * d : (d - 0.5f);
        }
    }
    if (pos1) {
        const float* pp = pred + p1 * 5;
        const float* gg = gt + p1 * 5;
#pragma unroll
        for (int j = 0; j < 5; ++j) {
            float d = fabsf(pp[j] - gg[j]);
            sl += (d < 1.f) ? 0.5f * d * d : (d - 0.5f);
        }
    }

    // ---- prior 0: 21-class lse + logp[lab] gather via selects
    float s0 = 0.f, cl0 = 0.f;
#define KS(Q, J, IDX, LAB, SACC, CACC) { const float v_ = Q[J]; \
        SACC += fexp2(v_ * 1.44269504f); \
        CACC = ((IDX) == (LAB)) ? v_ : CACC; }
    KS(A0,0,0,lab0,s0,cl0) KS(A0,1,1,lab0,s0,cl0) KS(A0,2,2,lab0,s0,cl0) KS(A0,3,3,lab0,s0,cl0)
    KS(A1,0,4,lab0,s0,cl0) KS(A1,1,5,lab0,s0,cl0) KS(A1,2,6,lab0,s0,cl0) KS(A1,3,7,lab0,s0,cl0)
    KS(A2,0,8,lab0,s0,cl0) KS(A2,1,9,lab0,s0,cl0) KS(A2,2,10,lab0,s0,cl0) KS(A2,3,11,lab0,s0,cl0)
    KS(A3,0,12,lab0,s0,cl0) KS(A3,1,13,lab0,s0,cl0) KS(A3,2,14,lab0,s0,cl0) KS(A3,3,15,lab0,s0,cl0)
    KS(A4,0,16,lab0,s0,cl0) KS(A4,1,17,lab0,s0,cl0) KS(A4,2,18,lab0,s0,cl0) KS(A4,3,19,lab0,s0,cl0)
    { const float v_ = a20; s0 += fexp2(v_ * 1.44269504f); cl0 = (20 == lab0) ? v_ : cl0; }
    const float lse0 = 0.6931471805599453f * flog2(s0);
    const float mining0 = fmaxf(lse0 - A0[0], 0.f);
    keys[p0] = pos0 ? 0u : __float_as_uint(mining0);
    float ce = pos0 ? (lse0 - cl0) : 0.f;
    int cnt = pos0 ? 1 : 0;

    // ---- prior 1
    float s1 = 0.f, cl1 = 0.f;
    KS(B0,0,0,lab1,s1,cl1) KS(B0,1,1,lab1,s1,cl1) KS(B0,2,2,lab1,s1,cl1) KS(B0,3,3,lab1,s1,cl1)
    KS(B1,0,4,lab1,s1,cl1) KS(B1,1,5,lab1,s1,cl1) KS(B1,2,6,lab1,s1,cl1) KS(B1,3,7,lab1,s1,cl1)
    KS(B2,0,8,lab1,s1,cl1) KS(B2,1,9,lab1,s1,cl1) KS(B2,2,10,lab1,s1,cl1) KS(B2,3,11,lab1,s1,cl1)
    KS(B3,0,12,lab1,s1,cl1) KS(B3,1,13,lab1,s1,cl1) KS(B3,2,14,lab1,s1,cl1) KS(B3,3,15,lab1,s1,cl1)
    KS(B4,0,16,lab1,s1,cl1) KS(B4,1,17,lab1,s1,cl1) KS(B4,2,18,lab1,s1,cl1) KS(B4,3,19,lab1,s1,cl1)
    { const float v_ = b20; s1 += fexp2(v_ * 1.44269504f); cl1 = (20 == lab1) ? v_ : cl1; }
#undef KS
    const float lse1 = 0.6931471805599453f * flog2(s1);
    const float mining1 = fmaxf(lse1 - B0[0], 0.f);
    keys[p1] = pos1 ? 0u : __float_as_uint(mining1);
    ce += pos1 ? (lse1 - cl1) : 0.f;
    cnt += pos1 ? 1 : 0;

    // ---- deterministic block reduction (fixed trees)
#pragma unroll
    for (int d = 32; d > 0; d >>= 1) {
        ce  += __shfl_down(ce, d);
        sl  += __shfl_down(sl, d);
        cnt += __shfl_down(cnt, d);
    }
    if (lane == 0) { wce[wid] = ce; wsl[wid] = sl; wcnt[wid] = cnt; }
    __syncthreads();
    if (tid == 0) {
        float tce = 0.f, tsl = 0.f; int tc = 0;
#pragma unroll
        for (int w = 0; w < 4; ++w) { tce += wce[w]; tsl += wsl[w]; tc += wcnt[w]; }
        pce[blockIdx.x]  = tce;
        psl1[blockIdx.x] = tsl;
        pcnt[blockIdx.x] = tc;     // non-atomic per-block count
    }
}

// ---------------------------------------------------------------------------
// Suffix-scan over 2048 bins (2 bins/thread) + crossing pick (level 2).
// ---------------------------------------------------------------------------
template <class GET>
__device__ __forceinline__ void sscan2048(
    GET get, unsigned* ss, unsigned* swsum,
    int* s_bin, int* s_above, unsigned want, int tid, int lane, int wid)
{
    const int b0 = 2047 - 2 * tid;     // descending scan order
    const int b1 = 2046 - 2 * tid;
    const unsigned m0 = get(b0), m1 = get(b1);
    unsigned v = m0 + m1;
#pragma unroll
    for (int d = 1; d < 64; d <<= 1) {
        unsigned u = __shfl_up(v, d);
        if (lane >= d) v += u;
    }
    if (lane == 63) swsum[wid] = v;
    __syncthreads();
    if (wid == 0) {
        unsigned wv = (lane < 16) ? swsum[lane] : 0;
#pragma unroll
        for (int d = 1; d < 16; d <<= 1) {
            unsigned u = __shfl_up(wv, d);
            if (lane >= d) wv += u;
        }
        if (lane < 16) swsum[lane] = wv;
    }
    __syncthreads();
    const unsigned off = wid ? swsum[wid - 1] : 0;
    const unsigned incl = off + v;     // suffix through b1
    const unsigned sb0 = incl - m1;    // suffix through b0
    ss[b0] = sb0;
    ss[b1] = incl;
    __syncthreads();
    if (sb0 >= want && (b0 == 2047 || ss[b0 + 1] < want)) {
        *s_bin = b0; *s_above = (b0 == 2047) ? 0 : (int)ss[b0 + 1];
    }
    if (incl >= want && ss[b1 + 1] < want) {
        *s_bin = b1; *s_above = (int)ss[b1 + 1];
    }
    __syncthreads();
}

// ---------------------------------------------------------------------------
// K2 v9: level-1 hist -> 256 exponent-byte bins x 64 copies (copy = lane):
// addr (bin<<6)|lane is always 2-lanes/bank, zero same-address collisions
// regardless of key concentration. Level 2 refines bits[23:13]; in-bin mean
// tail on the 19-bit prefix (error ~1e-3 << 0.39). Fence-free k3 fold kept.
// ---------------------------------------------------------------------------
__global__ __launch_bounds__(K2T, 8) void k2_select(
    const unsigned* __restrict__ keys, const int* __restrict__ pcnt,
    const float* __restrict__ pce, const float* __restrict__ psl1,
    double* __restrict__ gsum, unsigned* __restrict__ done,
    float* __restrict__ out)
{
    const int b = blockIdx.x;
    const int tid = threadIdx.x;
    const int lane = tid & 63;
    const int wid = tid >> 6;
    const unsigned* rk = keys + (size_t)b * NN;

    __shared__ unsigned h1[256 * 64];   // 64 KB: L1 = 256 bins x 64 copies;
                                        // reused by L2 as 2048 bins x 2 copies
    __shared__ unsigned tot[256];       // level-1 bin totals
    __shared__ unsigned ss[2048];       // suffix sums (L1 uses [0,256))
    __shared__ unsigned swsum[16];
    __shared__ double sdA[16], sdB[16];
    __shared__ int sdI[16];
    __shared__ int s_bin, s_above, s_last;
    __shared__ unsigned s_want;

    // ---- one coalesced read: 8 x uint4 per thread -> 32 keys in VGPRs
    uint4 kv[8];
    const uint4* rk4 = reinterpret_cast<const uint4*>(rk);
#pragma unroll
    for (int j = 0; j < 8; ++j) kv[j] = rk4[tid + j * K2T];

    // want = min(3 * row positives, NN)
    if (wid == 0) {
        int c = pcnt[b * BLKROW + lane];          // BLKROW == 64 == wave
#pragma unroll
        for (int d = 32; d > 0; d >>= 1) c += __shfl_down(c, d);
        if (lane == 0) s_want = (unsigned)((3 * c > NN) ? NN : 3 * c);
    }
    for (int i = tid; i < 256 * 64; i += K2T) h1[i] = 0;
    __syncthreads();
    const unsigned want = s_want;

    double rowval = 0.0;    // this row's selected-negative CE sum (tid 0 only)
    if (want > 0) {
        // ---- level 1: 256-bin hist of the exponent byte, copy = lane.
        // (bin<<6)|lane -> bank = lane%32: 2 lanes/bank, no same-address.
#pragma unroll
        for (int j = 0; j < 8; ++j) {
            atomicAdd(&h1[((kv[j].x >> 24) << 6) | lane], 1u);
            atomicAdd(&h1[((kv[j].y >> 24) << 6) | lane], 1u);
            atomicAdd(&h1[((kv[j].z >> 24) << 6) | lane], 1u);
            atomicAdd(&h1[((kv[j].w >> 24) << 6) | lane], 1u);
        }
        __syncthreads();

        // ---- totals: 4 threads/bin, each sums 16 copies, 2x shfl_xor merge
        {
            const int bn = tid >> 2;
            const int part = tid & 3;
            const unsigned* hp = &h1[(bn << 6) + (part << 4)];
            unsigned mv = 0;
#pragma unroll
            for (int i = 0; i < 16; ++i) mv += hp[i];
            mv += __shfl_xor(mv, 1);
            mv += __shfl_xor(mv, 2);
            if (part == 0) tot[bn] = mv;
        }
        __syncthreads();

        // ---- level-1 scan: 256 bins descending (threads 0..255 own bins)
        {
            const int bn = 255 - tid;             // valid for tid < 256
            unsigned v = (tid < 256) ? tot[bn] : 0;
#pragma unroll
            for (int d = 1; d < 64; d <<= 1) {
                unsigned u = __shfl_up(v, d);
                if (lane >= d) v += u;
            }
            if (lane == 63) swsum[wid] = v;
            __syncthreads();
            if (wid == 0) {
                unsigned wv = (lane < 16) ? swsum[lane] : 0;
#pragma unroll
                for (int d = 1; d < 16; d <<= 1) {
                    unsigned u = __shfl_up(wv, d);
                    if (lane >= d) wv += u;
                }
                if (lane < 16) swsum[lane] = wv;
            }
            __syncthreads();
            const unsigned incl = (wid ? swsum[wid - 1] : 0) + v;
            if (tid < 256) ss[bn] = incl;
            __syncthreads();
            if (tid < 256 && incl >= want && (bn == 255 || ss[bn + 1] < want)) {
                s_bin = bn; s_above = (bn == 255) ? 0 : (int)ss[bn + 1];
            }
            __syncthreads();
        }
        const unsigned bsel1 = (unsigned)s_bin;
        const unsigned want1 = want - (unsigned)s_above;

        // ---- level 2: bits[23:13] of in-bin keys (2048 bins, 2 copies)
        for (int i = tid; i < 4096; i += K2T) h1[i] = 0;
        __syncthreads();
        const unsigned c2 = lane & 1;
#pragma unroll
        for (int j = 0; j < 8; ++j) {
#define L2ADD(K) if (((K) >> 24) == bsel1) \
            atomicAdd(&h1[((((K) >> 13) & 0x7FFu) << 1) | c2], 1u);
            L2ADD(kv[j].x) L2ADD(kv[j].y) L2ADD(kv[j].z) L2ADD(kv[j].w)
#undef L2ADD
        }
        __syncthreads();
        sscan2048([&](int bn) { return h1[bn << 1] + h1[(bn << 1) | 1]; },
                  ss, swsum, &s_bin, &s_above, want1, tid, lane, wid);
        const unsigned bsel2 = (unsigned)s_bin;
        const unsigned want2 = want1 - (unsigned)s_above;   // 1 <= want2 <= cnt2
        const unsigned pref = (bsel1 << 11) | bsel2;        // key bits[31:13]

        // ---- final register pass: exact sum above bin + in-bin sum/count
        double aboveS = 0.0, inS = 0.0;
        int inC = 0;
#pragma unroll
        for (int j = 0; j < 8; ++j) {
#define FIN(K) { const unsigned hp = (K) >> 13; \
            if (hp > pref) aboveS += (double)__uint_as_float(K); \
            else if (hp == pref) { inS += (double)__uint_as_float(K); inC++; } }
            FIN(kv[j].x) FIN(kv[j].y) FIN(kv[j].z) FIN(kv[j].w)
#undef FIN
        }
#pragma unroll
        for (int d = 32; d > 0; d >>= 1) {
            aboveS += __shfl_down(aboveS, d);
            inS    += __shfl_down(inS, d);
            inC    += __shfl_down(inC, d);
        }
        if (lane == 0) { sdA[wid] = aboveS; sdB[wid] = inS; sdI[wid] = inC; }
        __syncthreads();
        if (tid == 0) {
            double tA = 0.0, tB = 0.0; int tC = 0;
#pragma unroll
            for (int w = 0; w < 16; ++w) { tA += sdA[w]; tB += sdB[w]; tC += sdI[w]; }
            // top-want2 of in-bin keys ~ want2 * mean (19-bit shared prefix)
            rowval = tA + tB * ((double)want2 / (double)tC);
        }
    }

    // ---- fence-free completion (device-scope atomics; data-dependent order)
    if (tid == 0) {
        const double oldv = atomicAdd(gsum, rowval);
        unsigned inc = (__double_as_longlong(oldv) == 0x7FF7DEADBEEF0123LL)
                           ? 2u : 1u;   // always 1; unprovable -> dep kept
        const unsigned old = atomicAdd(done, inc);
        s_last = (old == BB - 1) ? 1 : 0;
    }
    __syncthreads();

    // ---- last block: global reduction of k1 partials + output write
    if (s_last) {
        double ce = 0.0, sl = 0.0; int np = 0;
        for (int i = tid; i < K1_GRID; i += K2T) {   // 2 iterations
            ce += (double)pce[i];
            sl += (double)psl1[i];
            np += pcnt[i];
        }
#pragma unroll
        for (int d = 32; d > 0; d >>= 1) {
            ce += __shfl_down(ce, d);
            sl += __shfl_down(sl, d);
            np += __shfl_down(np, d);
        }
        if (lane == 0) { sdA[wid] = ce; sdB[wid] = sl; sdI[wid] = np; }
        __syncthreads();
        if (tid == 0) {
            double tce = 0.0, tsl = 0.0; int tnp = 0;
#pragma unroll
            for (int w = 0; w < 16; ++w) { tce += sdA[w]; tsl += sdB[w]; tnp += sdI[w]; }
            const double ns = atomicAdd(gsum, 0.0);   // full sum (all 32 done)
            const double npos = (double)tnp;
            out[0] = (float)(tsl / npos);             // smooth_l1_loss / n_pos
            out[1] = (float)((tce + ns) / npos);      // classification_loss / n_pos
        }
    }
}

// ---------------------------------------------------------------------------
extern "C" void kernel_launch(void* const* d_in, const int* in_sizes, int n_in,
                              void* d_out, int out_size, void* d_ws, size_t ws_size,
                              hipStream_t stream)
{
    const float* conf   = (const float*)d_in[0];
    const float* pred   = (const float*)d_in[1];
    const int*   labels = (const int*)d_in[2];
    const float* gt     = (const float*)d_in[3];
    float* out = (float*)d_out;

    char* ws = (char*)d_ws;
    unsigned* keys = (unsigned*)ws;                  // 4 MB
    float*    pce  = (float*)(ws + 4194304);         // 8 KB
    float*    psl1 = (float*)(ws + 4202496);         // 8 KB
    int*      pcnt = (int*)(ws + 4210688);           // 8 KB
    double*   gsum = (double*)(ws + 4218880);        // 8 B
    unsigned* done = (unsigned*)(ws + 4218888);      // 4 B

    k1_compute<<<K1_GRID, K1_BLK, 0, stream>>>(conf, pred, labels, gt,
                                               keys, pce, psl1, pcnt,
                                               gsum, done);
    k2_select<<<BB, K2T, 0, stream>>>(keys, pcnt, pce, psl1,
                                      gsum, done, out);
}